// Round 8
// baseline (161.112 us; speedup 1.0000x reference)
//
#include <hip/hip_runtime.h>
#include <hip/hip_bf16.h>

// ---------------------------------------------------------------------------
// CrossAttention: out = softmax((x Wq)(ctx Wk)^T * scale) (ctx Wv) Wo
// B=2, N=M=2048, H=16, D=64, QD=INNER=1024. fp32 in/out, bf16 MFMA inside.
// R8: GEMMs — B-operand loaded global->register (L2-resident weights, 2-deep
// named dbuf) skipping LDS; A-tile LDS with XOR granule swizzle (stage source
// pre-swizzled, read swizzled). Halves LDS traffic; 8-way->2-way conflicts.
// Attention unchanged from R7.
// ---------------------------------------------------------------------------

typedef __attribute__((ext_vector_type(8))) __bf16    bf16x8;
typedef __attribute__((ext_vector_type(4))) __bf16    bf16x4;
typedef __attribute__((ext_vector_type(4))) float     f32x4;

#define B_    2
#define H_    16
#define N_    2048
#define M_    2048
#define D_    64
#define QD_   1024

// 0.125 * log2(e): folds softmax scale and exp->exp2 conversion into Q
#define QSCALE 0.18033688011112042f

// direct global->LDS async copy, 16B per lane; LDS dest = wave-uniform base + lane*16
__device__ __forceinline__ void gld16(const __bf16* g, __bf16* l) {
    __builtin_amdgcn_global_load_lds(
        (const __attribute__((address_space(1))) unsigned int*)(g),
        (__attribute__((address_space(3))) unsigned int*)(l), 16, 0, 0);
}

// ---------------------------------------------------------------------------
// fused f32->bf16 convert for x (z=0) and context (z=1)
// ---------------------------------------------------------------------------
__global__ __launch_bounds__(256) void cvt2_f32_bf16(const float* __restrict__ x,
                                                     const float* __restrict__ ctx,
                                                     __bf16* __restrict__ xb,
                                                     __bf16* __restrict__ cb) {
    const float* src = blockIdx.y ? ctx : x;
    __bf16*      dst = blockIdx.y ? cb  : xb;
    int i = (blockIdx.x * 256 + threadIdx.x) * 4;
    float4 v = *reinterpret_cast<const float4*>(src + i);
    bf16x4 o;
    o.x = (__bf16)v.x; o.y = (__bf16)v.y; o.z = (__bf16)v.z; o.w = (__bf16)v.w;
    *reinterpret_cast<bf16x4*>(dst + i) = o;
}

// ---------------------------------------------------------------------------
// fused weight transpose+convert: Wt[o][i] = W[i][o], z selects which weight
// ---------------------------------------------------------------------------
__global__ __launch_bounds__(256) void transpose4_cvt(const float* __restrict__ w0,
                                                      const float* __restrict__ w1,
                                                      const float* __restrict__ w2,
                                                      const float* __restrict__ w3,
                                                      __bf16* __restrict__ t0,
                                                      __bf16* __restrict__ t1,
                                                      __bf16* __restrict__ t2,
                                                      __bf16* __restrict__ t3) {
    __shared__ float tile[64][65];
    const int z = blockIdx.z;
    const float* in = (z == 0) ? w0 : (z == 1) ? w1 : (z == 2) ? w2 : w3;
    __bf16*     out = (z == 0) ? t0 : (z == 1) ? t1 : (z == 2) ? t2 : t3;
    const int i0 = blockIdx.x * 64;
    const int o0 = blockIdx.y * 64;
    const int t  = threadIdx.x;
    const int r  = t >> 4;
    const int c4 = (t & 15) * 4;
#pragma unroll
    for (int p = 0; p < 4; ++p) {
        int row = p * 16 + r;
        float4 v = *reinterpret_cast<const float4*>(in + (size_t)(i0 + row) * QD_ + o0 + c4);
        tile[row][c4 + 0] = v.x; tile[row][c4 + 1] = v.y;
        tile[row][c4 + 2] = v.z; tile[row][c4 + 3] = v.w;
    }
    __syncthreads();
#pragma unroll
    for (int p = 0; p < 4; ++p) {
        int orow = p * 16 + r;
        bf16x4 o;
        o.x = (__bf16)tile[c4 + 0][orow];
        o.y = (__bf16)tile[c4 + 1][orow];
        o.z = (__bf16)tile[c4 + 2][orow];
        o.w = (__bf16)tile[c4 + 3][orow];
        *reinterpret_cast<bf16x4*>(out + (size_t)(o0 + orow) * QD_ + i0 + c4) = o;
    }
}

// ---------------------------------------------------------------------------
// GEMM core R8: 128x128 tile, 4 waves (2x2), wave = 64x64 (4x4 frags), BK=32.
// A staged in LDS (stage-ahead dbuf, XOR granule swizzle g^=(row>>1)&3,
// pre-swizzled global source + swizzled ds_read — both-sides involution).
// B fragments loaded global->VGPR (L2-resident weights) with named 2-deep
// double-buffer bA/bB. One barrier per K-step.
// ---------------------------------------------------------------------------
#define GEMM_BODY(A_, Bt_)                                                                     \
    __shared__ __align__(16) __bf16 Alds[2][128 * 32];                                         \
    const int tid  = threadIdx.x;                                                              \
    const int wid  = tid >> 6;                                                                 \
    const int lane = tid & 63;                                                                 \
    const int l15  = lane & 15;                                                                \
    const int lg   = lane >> 4;                                                                \
    const int wr   = wid >> 1;                                                                 \
    const int wc   = wid & 1;                                                                  \
    const int rowBase = blockIdx.x * 128;                                                      \
    const int colBase = blockIdx.y * 128;                                                      \
    const int srow = wid * 32 + (lane >> 2);                                                   \
    const int sg   = (((lane & 3) ^ ((srow >> 1) & 3))) * 8;  /* pre-swizzled src granule */   \
    const __bf16* Ag  = A_  + (size_t)(rowBase + srow) * QD_ + sg;                             \
    const __bf16* Ag2 = Ag  + (size_t)16 * QD_;   /* (srow+16)>>1 & 3 == (srow>>1)&3 */        \
    const __bf16* Bg  = Bt_ + (size_t)(colBase + wc * 64 + l15) * QD_ + lg * 8;                \
    const int sOff  = (wid * 32) * 32;                                                         \
    const int sOff2 = sOff + 16 * 32;                                                          \
    int aoff[4];                                                                               \
    _Pragma("unroll")                                                                          \
    for (int m = 0; m < 4; ++m) {                                                              \
        int row = wr * 64 + m * 16 + l15;                                                      \
        aoff[m] = row * 32 + ((lg ^ ((row >> 1) & 3)) * 8);                                    \
    }                                                                                          \
    f32x4 acc[4][4] = {};                                                                      \
    bf16x8 bA0, bA1, bA2, bA3, bB0, bB1, bB2, bB3;                                             \
    gld16(Ag,  &Alds[0][sOff]);                                                                \
    gld16(Ag2, &Alds[0][sOff2]);                                                               \
    bA0 = *reinterpret_cast<const bf16x8*>(Bg);                                                \
    bA1 = *reinterpret_cast<const bf16x8*>(Bg + (size_t)16 * QD_);                             \
    bA2 = *reinterpret_cast<const bf16x8*>(Bg + (size_t)32 * QD_);                             \
    bA3 = *reinterpret_cast<const bf16x8*>(Bg + (size_t)48 * QD_);                             \
    __syncthreads();                                                                           \
    for (int t = 0; t < 32; t += 2) {                                                          \
        if (t + 1 < 32) {                                                                      \
            int kn = (t + 1) * 32;                                                             \
            gld16(Ag + kn,  &Alds[1][sOff]);                                                   \
            gld16(Ag2 + kn, &Alds[1][sOff2]);                                                  \
            bB0 = *reinterpret_cast<const bf16x8*>(Bg + kn);                                   \
            bB1 = *reinterpret_cast<const bf16x8*>(Bg + (size_t)16 * QD_ + kn);                \
            bB2 = *reinterpret_cast<const bf16x8*>(Bg + (size_t)32 * QD_ + kn);                \
            bB3 = *reinterpret_cast<const bf16x8*>(Bg + (size_t)48 * QD_ + kn);                \
        }                                                                                      \
        GCOMPUTE(0, bA0, bA1, bA2, bA3)                                                        \
        __syncthreads();                                                                       \
        if (t + 2 < 32) {                                                                      \
            int kn = (t + 2) * 32;                                                             \
            gld16(Ag + kn,  &Alds[0][sOff]);                                                   \
            gld16(Ag2 + kn, &Alds[0][sOff2]);                                                  \
            bA0 = *reinterpret_cast<const bf16x8*>(Bg + kn);                                   \
            bA1 = *reinterpret_cast<const bf16x8*>(Bg + (size_t)16 * QD_ + kn);                \
            bA2 = *reinterpret_cast<const bf16x8*>(Bg + (size_t)32 * QD_ + kn);                \
            bA3 = *reinterpret_cast<const bf16x8*>(Bg + (size_t)48 * QD_ + kn);                \
        }                                                                                      \
        GCOMPUTE(1, bB0, bB1, bB2, bB3)                                                        \
        __syncthreads();                                                                       \
    }

#define GCOMPUTE(BUF, B0, B1, B2, B3)                                                          \
    {                                                                                          \
        bf16x8 a[4];                                                                           \
        _Pragma("unroll")                                                                      \
        for (int m = 0; m < 4; ++m)                                                            \
            a[m] = *reinterpret_cast<const bf16x8*>(&Alds[BUF][aoff[m]]);                      \
        _Pragma("unroll")                                                                      \
        for (int m = 0; m < 4; ++m) {                                                          \
            acc[m][0] = __builtin_amdgcn_mfma_f32_16x16x32_bf16(a[m], B0, acc[m][0], 0, 0, 0); \
            acc[m][1] = __builtin_amdgcn_mfma_f32_16x16x32_bf16(a[m], B1, acc[m][1], 0, 0, 0); \
            acc[m][2] = __builtin_amdgcn_mfma_f32_16x16x32_bf16(a[m], B2, acc[m][2], 0, 0, 0); \
            acc[m][3] = __builtin_amdgcn_mfma_f32_16x16x32_bf16(a[m], B3, acc[m][3], 0, 0, 0); \
        }                                                                                      \
    }

// fused Q/K/V projection: blockIdx.z selects {Q (scaled), K, V^T} output
__global__ __launch_bounds__(256) void gemm_qkv(const __bf16* __restrict__ xb,
                                                const __bf16* __restrict__ cb,
                                                const __bf16* __restrict__ Wtq,
                                                const __bf16* __restrict__ Wtk,
                                                const __bf16* __restrict__ Wtv,
                                                __bf16* __restrict__ Qb,
                                                __bf16* __restrict__ Kb,
                                                __bf16* __restrict__ Vt) {
    const int z = blockIdx.z;
    const __bf16* Asel = (z == 0) ? xb : cb;
    const __bf16* Bsel = (z == 0) ? Wtq : (z == 1) ? Wtk : Wtv;
    GEMM_BODY(Asel, Bsel)
#pragma unroll
    for (int m = 0; m < 4; ++m)
#pragma unroll
        for (int n = 0; n < 4; ++n)
#pragma unroll
            for (int r = 0; r < 4; ++r) {
                int rr = rowBase + wr * 64 + m * 16 + lg * 4 + r;
                int cc = colBase + wc * 64 + n * 16 + l15;
                float v = acc[m][n][r];
                int b_ = rr >> 11, nn = rr & 2047, hh = cc >> 6, dd = cc & 63;
                if (z == 0) {
                    Qb[((size_t)(b_ * H_ + hh) * N_ + nn) * D_ + dd] = (__bf16)(v * QSCALE);
                } else if (z == 1) {
                    Kb[((size_t)(b_ * H_ + hh) * N_ + nn) * D_ + dd] = (__bf16)v;
                } else {
                    Vt[((size_t)(b_ * H_ + hh) * D_ + dd) * M_ + nn] = (__bf16)v;
                }
            }
}

// final projection: AO @ Wto -> f32 out
__global__ __launch_bounds__(256) void gemm_out(const __bf16* __restrict__ AO,
                                                const __bf16* __restrict__ Wto,
                                                float* __restrict__ out) {
    GEMM_BODY(AO, Wto)
#pragma unroll
    for (int m = 0; m < 4; ++m)
#pragma unroll
        for (int n = 0; n < 4; ++n)
#pragma unroll
            for (int r = 0; r < 4; ++r) {
                int rr = rowBase + wr * 64 + m * 16 + lg * 4 + r;
                int cc = colBase + wc * 64 + n * 16 + l15;
                out[(size_t)rr * QD_ + cc] = acc[m][n][r];
            }
}

// ---------------------------------------------------------------------------
// Attention (R7, unchanged). Grid 512 (XCD-swizzled), 8 waves x 16 q-rows,
// K/V LDS dbuf (32 KB), XOR swizzle via pre-swizzled global source, swapped
// QK^T -> P lane-local, row-sums via ones-MFMA, exp2 with pre-scaled Q.
// ---------------------------------------------------------------------------
__global__ __launch_bounds__(512, 4) void attn_kernel(const __bf16* __restrict__ Q,
                                                      const __bf16* __restrict__ K,
                                                      const __bf16* __restrict__ Vt,
                                                      __bf16* __restrict__ AO) {
    __shared__ __align__(16) __bf16 Klds[2][4096];
    __shared__ __align__(16) __bf16 Vlds[2][4096];

    const int logical = (blockIdx.x & 7) * 64 + (blockIdx.x >> 3);
    const int qt   = logical & 15;
    const int bh   = logical >> 4;
    const int b    = bh >> 4;
    const int h    = bh & 15;
    const int wid  = threadIdx.x >> 6;     // 0..7
    const int lane = threadIdx.x & 63;
    const int l15  = lane & 15;
    const int lg   = lane >> 4;
    const int qbase = qt * 128 + wid * 16;

    const __bf16* Qp = Q  + ((size_t)bh * N_ + qbase) * D_;
    const __bf16* Kp = K  + (size_t)bh * M_ * D_;
    const __bf16* Vp = Vt + (size_t)bh * D_ * M_;

    const int rg   = lane >> 3;
    const int ch   = lane & 7;
    const int skw  = (rg & 3) | ((wid & 1) << 2);   // sK(w*8+rg)
    const int kc   = (ch ^ skw) << 3;
    const int vc   = (ch ^ rg) << 3;                // sV(w*8+rg) = rg
    const int srow = wid * 8 + rg;
    const int ldst = wid * 512;

#define STAGE(BUF, KV0)                                                        \
    gld16(Kp + (size_t)((KV0) + srow) * D_ + kc, &Klds[BUF][ldst]);            \
    gld16(Vp + (size_t)srow * M_ + (KV0) + vc,  &Vlds[BUF][ldst]);

    const int rm0 = ((l15 >> 2) * 8) + (l15 & 3);   // permuted K row (QK^T swap)
    const int sq  = (l15 & 7) << 3;
    const int ak00 = rm0 * 64 + (( 0 + lg * 8) ^ sq);
    const int ak01 = rm0 * 64 + ((32 + lg * 8) ^ sq);
    const int ak10 = ak00 + 256;
    const int ak11 = ak01 + 256;
    const int av0 = l15 * 64 + (( 0 + lg * 8) ^ sq);
    const int av1 = l15 * 64 + ((32 + lg * 8) ^ sq);

    bf16x8 qf0 = *reinterpret_cast<const bf16x8*>(Qp + (size_t)l15 * D_ +      lg * 8);
    bf16x8 qf1 = *reinterpret_cast<const bf16x8*>(Qp + (size_t)l15 * D_ + 32 + lg * 8);

    bf16x8 onesf;
#pragma unroll
    for (int j = 0; j < 8; ++j) onesf[j] = (__bf16)1.0f;

    f32x4 o0 = {}, o1 = {}, o2 = {}, o3 = {}, ors = {};

#define COMPUTE(KB, VB, KOFF, AV)                                                               \
    {                                                                                           \
        bf16x8 k00 = *reinterpret_cast<const bf16x8*>((KB) + ak00 + (KOFF));                    \
        bf16x8 k01 = *reinterpret_cast<const bf16x8*>((KB) + ak01 + (KOFF));                    \
        bf16x8 k10 = *reinterpret_cast<const bf16x8*>((KB) + ak10 + (KOFF));                    \
        bf16x8 k11 = *reinterpret_cast<const bf16x8*>((KB) + ak11 + (KOFF));                    \
        bf16x8 v0  = *reinterpret_cast<const bf16x8*>((VB) + (AV));                             \
        bf16x8 v1  = *reinterpret_cast<const bf16x8*>((VB) + (AV) + 1024);                      \
        bf16x8 v2  = *reinterpret_cast<const bf16x8*>((VB) + (AV) + 2048);                      \
        bf16x8 v3  = *reinterpret_cast<const bf16x8*>((VB) + (AV) + 3072);                      \
        f32x4 s0 = {}, s1 = {};                                                                 \
        s0 = __builtin_amdgcn_mfma_f32_16x16x32_bf16(k00, qf0, s0, 0, 0, 0);                    \
        s0 = __builtin_amdgcn_mfma_f32_16x16x32_bf16(k01, qf1, s0, 0, 0, 0);                    \
        s1 = __builtin_amdgcn_mfma_f32_16x16x32_bf16(k10, qf0, s1, 0, 0, 0);                    \
        s1 = __builtin_amdgcn_mfma_f32_16x16x32_bf16(k11, qf1, s1, 0, 0, 0);                    \
        bf16x8 pf;                                                                              \
        pf[0] = (__bf16)__builtin_amdgcn_exp2f(s0[0]);                                          \
        pf[1] = (__bf16)__builtin_amdgcn_exp2f(s0[1]);                                          \
        pf[2] = (__bf16)__builtin_amdgcn_exp2f(s0[2]);                                          \
        pf[3] = (__bf16)__builtin_amdgcn_exp2f(s0[3]);                                          \
        pf[4] = (__bf16)__builtin_amdgcn_exp2f(s1[0]);                                          \
        pf[5] = (__bf16)__builtin_amdgcn_exp2f(s1[1]);                                          \
        pf[6] = (__bf16)__builtin_amdgcn_exp2f(s1[2]);                                          \
        pf[7] = (__bf16)__builtin_amdgcn_exp2f(s1[3]);                                          \
        ors = __builtin_amdgcn_mfma_f32_16x16x32_bf16(pf, onesf, ors, 0, 0, 0);                 \
        o0 = __builtin_amdgcn_mfma_f32_16x16x32_bf16(pf, v0, o0, 0, 0, 0);                      \
        o1 = __builtin_amdgcn_mfma_f32_16x16x32_bf16(pf, v1, o1, 0, 0, 0);                      \
        o2 = __builtin_amdgcn_mfma_f32_16x16x32_bf16(pf, v2, o2, 0, 0, 0);                      \
        o3 = __builtin_amdgcn_mfma_f32_16x16x32_bf16(pf, v3, o3, 0, 0, 0);                      \
    }

    STAGE(0, 0)
    __syncthreads();

    for (int t = 0; t < 32; t += 2) {
        if (t + 1 < 32) { STAGE(1, (t + 1) * 64) }
        COMPUTE(Klds[0], Vlds[0], 0,    av0)
        COMPUTE(Klds[0], Vlds[0], 2048, av1)
        __syncthreads();
        if (t + 2 < 32) { STAGE(0, (t + 2) * 64) }
        COMPUTE(Klds[1], Vlds[1], 0,    av0)
        COMPUTE(Klds[1], Vlds[1], 2048, av1)
        __syncthreads();
    }
#undef STAGE
#undef COMPUTE

#pragma unroll
    for (int r = 0; r < 4; ++r) {
        float inv = 1.0f / ors[r];
        size_t row = ((size_t)b * N_ + qbase + lg * 4 + r) * QD_ + h * D_ + l15;
        AO[row +  0] = (__bf16)(o0[r] * inv);
        AO[row + 16] = (__bf16)(o1[r] * inv);
        AO[row + 32] = (__bf16)(o2[r] * inv);
        AO[row + 48] = (__bf16)(o3[r] * inv);
    }
}

// ---------------------------------------------------------------------------
extern "C" void kernel_launch(void* const* d_in, const int* in_sizes, int n_in,
                              void* d_out, int out_size, void* d_ws, size_t ws_size,
                              hipStream_t stream) {
    const float* x   = (const float*)d_in[0];
    const float* ctx = (const float*)d_in[1];
    const float* Wq  = (const float*)d_in[2];
    const float* Wk  = (const float*)d_in[3];
    const float* Wv  = (const float*)d_in[4];
    const float* Wo  = (const float*)d_in[5];

    char* ws = (char*)d_ws;
    __bf16* xb  = (__bf16*)(ws);                      // 0-8 MB
    __bf16* cb  = (__bf16*)(ws + (8u  << 20));        // 8-16 MB
    __bf16* Wtq = (__bf16*)(ws + (16u << 20));        // 16-18 MB
    __bf16* Wtk = (__bf16*)(ws + (18u << 20));        // 18-20
    __bf16* Wtv = (__bf16*)(ws + (20u << 20));        // 20-22
    __bf16* Wto = (__bf16*)(ws + (22u << 20));        // 22-24
    __bf16* Qb  = (__bf16*)(ws + (24u << 20));        // 24-32  [bh][2048][64], pre-scaled
    __bf16* Kb  = (__bf16*)(ws + (32u << 20));        // 32-40  [bh][2048][64]
    __bf16* Vt  = (__bf16*)(ws + (40u << 20));        // 40-48  [bh][64][2048]
    __bf16* AO  = (__bf16*)(ws + (48u << 20));        // 48-56  [4096][1024]

    cvt2_f32_bf16<<<dim3(4096, 2), 256, 0, stream>>>(x, ctx, xb, cb);
    transpose4_cvt<<<dim3(16, 16, 4), 256, 0, stream>>>(Wq, Wk, Wv, Wo, Wtq, Wtk, Wtv, Wto);
    gemm_qkv<<<dim3(32, 8, 3), 256, 0, stream>>>(xb, cb, Wtq, Wtk, Wtv, Qb, Kb, Vt);
    attn_kernel<<<512, 512, 0, stream>>>(Qb, Kb, Vt, AO);
    gemm_out<<<dim3(32, 8), 256, 0, stream>>>(AO, Wto, (float*)d_out);
}

// Round 9
// 122.802 us; speedup vs baseline: 1.3120x; 1.3120x over previous
//
#include <hip/hip_runtime.h>
#include <hip/hip_bf16.h>

// ---------------------------------------------------------------------------
// CrossAttention: out = softmax((x Wq)(ctx Wk)^T * scale) (ctx Wv) Wo
// B=2, N=M=2048, H=16, D=64, QD=INNER=1024. fp32 in/out, bf16 MFMA inside.
// R9: GEMMs = R6 structure (A+B staged via global_load_lds, stage-ahead dbuf,
// one barrier/K-step) + R8's XOR granule swizzle on BOTH operands
// (pre-swizzled global source + swizzled ds_read; proven conflict-free).
// Attention unchanged from R7.
// ---------------------------------------------------------------------------

typedef __attribute__((ext_vector_type(8))) __bf16    bf16x8;
typedef __attribute__((ext_vector_type(4))) __bf16    bf16x4;
typedef __attribute__((ext_vector_type(4))) float     f32x4;

#define B_    2
#define H_    16
#define N_    2048
#define M_    2048
#define D_    64
#define QD_   1024

// 0.125 * log2(e): folds softmax scale and exp->exp2 conversion into Q
#define QSCALE 0.18033688011112042f

// direct global->LDS async copy, 16B per lane; LDS dest = wave-uniform base + lane*16
__device__ __forceinline__ void gld16(const __bf16* g, __bf16* l) {
    __builtin_amdgcn_global_load_lds(
        (const __attribute__((address_space(1))) unsigned int*)(g),
        (__attribute__((address_space(3))) unsigned int*)(l), 16, 0, 0);
}

// ---------------------------------------------------------------------------
// fused f32->bf16 convert for x (z=0) and context (z=1)
// ---------------------------------------------------------------------------
__global__ __launch_bounds__(256) void cvt2_f32_bf16(const float* __restrict__ x,
                                                     const float* __restrict__ ctx,
                                                     __bf16* __restrict__ xb,
                                                     __bf16* __restrict__ cb) {
    const float* src = blockIdx.y ? ctx : x;
    __bf16*      dst = blockIdx.y ? cb  : xb;
    int i = (blockIdx.x * 256 + threadIdx.x) * 4;
    float4 v = *reinterpret_cast<const float4*>(src + i);
    bf16x4 o;
    o.x = (__bf16)v.x; o.y = (__bf16)v.y; o.z = (__bf16)v.z; o.w = (__bf16)v.w;
    *reinterpret_cast<bf16x4*>(dst + i) = o;
}

// ---------------------------------------------------------------------------
// fused weight transpose+convert: Wt[o][i] = W[i][o], z selects which weight
// ---------------------------------------------------------------------------
__global__ __launch_bounds__(256) void transpose4_cvt(const float* __restrict__ w0,
                                                      const float* __restrict__ w1,
                                                      const float* __restrict__ w2,
                                                      const float* __restrict__ w3,
                                                      __bf16* __restrict__ t0,
                                                      __bf16* __restrict__ t1,
                                                      __bf16* __restrict__ t2,
                                                      __bf16* __restrict__ t3) {
    __shared__ float tile[64][65];
    const int z = blockIdx.z;
    const float* in = (z == 0) ? w0 : (z == 1) ? w1 : (z == 2) ? w2 : w3;
    __bf16*     out = (z == 0) ? t0 : (z == 1) ? t1 : (z == 2) ? t2 : t3;
    const int i0 = blockIdx.x * 64;
    const int o0 = blockIdx.y * 64;
    const int t  = threadIdx.x;
    const int r  = t >> 4;
    const int c4 = (t & 15) * 4;
#pragma unroll
    for (int p = 0; p < 4; ++p) {
        int row = p * 16 + r;
        float4 v = *reinterpret_cast<const float4*>(in + (size_t)(i0 + row) * QD_ + o0 + c4);
        tile[row][c4 + 0] = v.x; tile[row][c4 + 1] = v.y;
        tile[row][c4 + 2] = v.z; tile[row][c4 + 3] = v.w;
    }
    __syncthreads();
#pragma unroll
    for (int p = 0; p < 4; ++p) {
        int orow = p * 16 + r;
        bf16x4 o;
        o.x = (__bf16)tile[c4 + 0][orow];
        o.y = (__bf16)tile[c4 + 1][orow];
        o.z = (__bf16)tile[c4 + 2][orow];
        o.w = (__bf16)tile[c4 + 3][orow];
        *reinterpret_cast<bf16x4*>(out + (size_t)(o0 + orow) * QD_ + i0 + c4) = o;
    }
}

// ---------------------------------------------------------------------------
// GEMM core R9: 128x128 tile, 4 waves (2x2), wave = 64x64 (4x4 frags), BK=32.
// A and B staged in LDS via gld16 (stage-ahead dbuf, one barrier per K-step)
// with XOR granule swizzle: LDS[row][g] holds global (row, g ^ ((row>>1)&3)).
// Stage pre-swizzles the GLOBAL source column; reads swizzle the LDS offset.
// ---------------------------------------------------------------------------
#define GEMM_BODY(A_, Bt_)                                                                     \
    __shared__ __align__(16) __bf16 Alds[2][128 * 32];                                         \
    __shared__ __align__(16) __bf16 Blds[2][128 * 32];                                         \
    const int tid  = threadIdx.x;                                                              \
    const int wid  = tid >> 6;                                                                 \
    const int lane = tid & 63;                                                                 \
    const int l15  = lane & 15;                                                                \
    const int lg   = lane >> 4;                                                                \
    const int wr   = wid >> 1;                                                                 \
    const int wc   = wid & 1;                                                                  \
    const int rowBase = blockIdx.x * 128;                                                      \
    const int colBase = blockIdx.y * 128;                                                      \
    const int srow = wid * 32 + (lane >> 2);                                                   \
    const int sg   = ((lane & 3) ^ ((srow >> 1) & 3)) * 8;  /* pre-swizzled src granule */     \
    const __bf16* Ag  = A_  + (size_t)(rowBase + srow) * QD_ + sg;                             \
    const __bf16* Ag2 = Ag  + (size_t)16 * QD_;   /* ((srow+16)>>1)&3 == (srow>>1)&3 */        \
    const __bf16* Bg  = Bt_ + (size_t)(colBase + srow) * QD_ + sg;                             \
    const __bf16* Bg2 = Bg  + (size_t)16 * QD_;                                                \
    const int sOff  = (wid * 32) * 32;                                                         \
    const int sOff2 = sOff + 16 * 32;                                                          \
    int aoff[4], boff[4];                                                                      \
    _Pragma("unroll")                                                                          \
    for (int m = 0; m < 4; ++m) {                                                              \
        int ra = wr * 64 + m * 16 + l15;                                                       \
        int rb = wc * 64 + m * 16 + l15;                                                       \
        aoff[m] = ra * 32 + ((lg ^ ((ra >> 1) & 3)) * 8);                                      \
        boff[m] = rb * 32 + ((lg ^ ((rb >> 1) & 3)) * 8);                                      \
    }                                                                                          \
    f32x4 acc[4][4] = {};                                                                      \
    gld16(Ag,  &Alds[0][sOff]);                                                                \
    gld16(Ag2, &Alds[0][sOff2]);                                                               \
    gld16(Bg,  &Blds[0][sOff]);                                                                \
    gld16(Bg2, &Blds[0][sOff2]);                                                               \
    __syncthreads();                                                                           \
    for (int t = 0; t < 32; t += 2) {                                                          \
        if (t + 1 < 32) {                                                                      \
            int kn = (t + 1) * 32;                                                             \
            gld16(Ag + kn,  &Alds[1][sOff]);                                                   \
            gld16(Ag2 + kn, &Alds[1][sOff2]);                                                  \
            gld16(Bg + kn,  &Blds[1][sOff]);                                                   \
            gld16(Bg2 + kn, &Blds[1][sOff2]);                                                  \
        }                                                                                      \
        GCOMPUTE(0)                                                                            \
        __syncthreads();                                                                       \
        if (t + 2 < 32) {                                                                      \
            int kn = (t + 2) * 32;                                                             \
            gld16(Ag + kn,  &Alds[0][sOff]);                                                   \
            gld16(Ag2 + kn, &Alds[0][sOff2]);                                                  \
            gld16(Bg + kn,  &Blds[0][sOff]);                                                   \
            gld16(Bg2 + kn, &Blds[0][sOff2]);                                                  \
        }                                                                                      \
        GCOMPUTE(1)                                                                            \
        __syncthreads();                                                                       \
    }

#define GCOMPUTE(BUF)                                                                          \
    {                                                                                          \
        bf16x8 a[4], b[4];                                                                     \
        _Pragma("unroll")                                                                      \
        for (int m = 0; m < 4; ++m)                                                            \
            a[m] = *reinterpret_cast<const bf16x8*>(&Alds[BUF][aoff[m]]);                      \
        _Pragma("unroll")                                                                      \
        for (int n = 0; n < 4; ++n)                                                            \
            b[n] = *reinterpret_cast<const bf16x8*>(&Blds[BUF][boff[n]]);                      \
        _Pragma("unroll")                                                                      \
        for (int m = 0; m < 4; ++m)                                                            \
            _Pragma("unroll")                                                                  \
            for (int n = 0; n < 4; ++n)                                                        \
                acc[m][n] = __builtin_amdgcn_mfma_f32_16x16x32_bf16(a[m], b[n], acc[m][n], 0, 0, 0); \
    }

// fused Q/K/V projection: blockIdx.z selects {Q (scaled), K, V^T} output
__global__ __launch_bounds__(256) void gemm_qkv(const __bf16* __restrict__ xb,
                                                const __bf16* __restrict__ cb,
                                                const __bf16* __restrict__ Wtq,
                                                const __bf16* __restrict__ Wtk,
                                                const __bf16* __restrict__ Wtv,
                                                __bf16* __restrict__ Qb,
                                                __bf16* __restrict__ Kb,
                                                __bf16* __restrict__ Vt) {
    const int z = blockIdx.z;
    const __bf16* Asel = (z == 0) ? xb : cb;
    const __bf16* Bsel = (z == 0) ? Wtq : (z == 1) ? Wtk : Wtv;
    GEMM_BODY(Asel, Bsel)
#pragma unroll
    for (int m = 0; m < 4; ++m)
#pragma unroll
        for (int n = 0; n < 4; ++n)
#pragma unroll
            for (int r = 0; r < 4; ++r) {
                int rr = rowBase + wr * 64 + m * 16 + lg * 4 + r;
                int cc = colBase + wc * 64 + n * 16 + l15;
                float v = acc[m][n][r];
                int b_ = rr >> 11, nn = rr & 2047, hh = cc >> 6, dd = cc & 63;
                if (z == 0) {
                    Qb[((size_t)(b_ * H_ + hh) * N_ + nn) * D_ + dd] = (__bf16)(v * QSCALE);
                } else if (z == 1) {
                    Kb[((size_t)(b_ * H_ + hh) * N_ + nn) * D_ + dd] = (__bf16)v;
                } else {
                    Vt[((size_t)(b_ * H_ + hh) * D_ + dd) * M_ + nn] = (__bf16)v;
                }
            }
}

// final projection: AO @ Wto -> f32 out
__global__ __launch_bounds__(256) void gemm_out(const __bf16* __restrict__ AO,
                                                const __bf16* __restrict__ Wto,
                                                float* __restrict__ out) {
    GEMM_BODY(AO, Wto)
#pragma unroll
    for (int m = 0; m < 4; ++m)
#pragma unroll
        for (int n = 0; n < 4; ++n)
#pragma unroll
            for (int r = 0; r < 4; ++r) {
                int rr = rowBase + wr * 64 + m * 16 + lg * 4 + r;
                int cc = colBase + wc * 64 + n * 16 + l15;
                out[(size_t)rr * QD_ + cc] = acc[m][n][r];
            }
}

// ---------------------------------------------------------------------------
// Attention (R7, unchanged). Grid 512 (XCD-swizzled), 8 waves x 16 q-rows,
// K/V LDS dbuf (32 KB), XOR swizzle via pre-swizzled global source, swapped
// QK^T -> P lane-local, row-sums via ones-MFMA, exp2 with pre-scaled Q.
// ---------------------------------------------------------------------------
__global__ __launch_bounds__(512, 4) void attn_kernel(const __bf16* __restrict__ Q,
                                                      const __bf16* __restrict__ K,
                                                      const __bf16* __restrict__ Vt,
                                                      __bf16* __restrict__ AO) {
    __shared__ __align__(16) __bf16 Klds[2][4096];
    __shared__ __align__(16) __bf16 Vlds[2][4096];

    const int logical = (blockIdx.x & 7) * 64 + (blockIdx.x >> 3);
    const int qt   = logical & 15;
    const int bh   = logical >> 4;
    const int b    = bh >> 4;
    const int h    = bh & 15;
    const int wid  = threadIdx.x >> 6;     // 0..7
    const int lane = threadIdx.x & 63;
    const int l15  = lane & 15;
    const int lg   = lane >> 4;
    const int qbase = qt * 128 + wid * 16;

    const __bf16* Qp = Q  + ((size_t)bh * N_ + qbase) * D_;
    const __bf16* Kp = K  + (size_t)bh * M_ * D_;
    const __bf16* Vp = Vt + (size_t)bh * D_ * M_;

    const int rg   = lane >> 3;
    const int ch   = lane & 7;
    const int skw  = (rg & 3) | ((wid & 1) << 2);   // sK(w*8+rg)
    const int kc   = (ch ^ skw) << 3;
    const int vc   = (ch ^ rg) << 3;                // sV(w*8+rg) = rg
    const int srow = wid * 8 + rg;
    const int ldst = wid * 512;

#define STAGE(BUF, KV0)                                                        \
    gld16(Kp + (size_t)((KV0) + srow) * D_ + kc, &Klds[BUF][ldst]);            \
    gld16(Vp + (size_t)srow * M_ + (KV0) + vc,  &Vlds[BUF][ldst]);

    const int rm0 = ((l15 >> 2) * 8) + (l15 & 3);   // permuted K row (QK^T swap)
    const int sq  = (l15 & 7) << 3;
    const int ak00 = rm0 * 64 + (( 0 + lg * 8) ^ sq);
    const int ak01 = rm0 * 64 + ((32 + lg * 8) ^ sq);
    const int ak10 = ak00 + 256;
    const int ak11 = ak01 + 256;
    const int av0 = l15 * 64 + (( 0 + lg * 8) ^ sq);
    const int av1 = l15 * 64 + ((32 + lg * 8) ^ sq);

    bf16x8 qf0 = *reinterpret_cast<const bf16x8*>(Qp + (size_t)l15 * D_ +      lg * 8);
    bf16x8 qf1 = *reinterpret_cast<const bf16x8*>(Qp + (size_t)l15 * D_ + 32 + lg * 8);

    bf16x8 onesf;
#pragma unroll
    for (int j = 0; j < 8; ++j) onesf[j] = (__bf16)1.0f;

    f32x4 o0 = {}, o1 = {}, o2 = {}, o3 = {}, ors = {};

#define COMPUTE(KB, VB, KOFF, AV)                                                               \
    {                                                                                           \
        bf16x8 k00 = *reinterpret_cast<const bf16x8*>((KB) + ak00 + (KOFF));                    \
        bf16x8 k01 = *reinterpret_cast<const bf16x8*>((KB) + ak01 + (KOFF));                    \
        bf16x8 k10 = *reinterpret_cast<const bf16x8*>((KB) + ak10 + (KOFF));                    \
        bf16x8 k11 = *reinterpret_cast<const bf16x8*>((KB) + ak11 + (KOFF));                    \
        bf16x8 v0  = *reinterpret_cast<const bf16x8*>((VB) + (AV));                             \
        bf16x8 v1  = *reinterpret_cast<const bf16x8*>((VB) + (AV) + 1024);                      \
        bf16x8 v2  = *reinterpret_cast<const bf16x8*>((VB) + (AV) + 2048);                      \
        bf16x8 v3  = *reinterpret_cast<const bf16x8*>((VB) + (AV) + 3072);                      \
        f32x4 s0 = {}, s1 = {};                                                                 \
        s0 = __builtin_amdgcn_mfma_f32_16x16x32_bf16(k00, qf0, s0, 0, 0, 0);                    \
        s0 = __builtin_amdgcn_mfma_f32_16x16x32_bf16(k01, qf1, s0, 0, 0, 0);                    \
        s1 = __builtin_amdgcn_mfma_f32_16x16x32_bf16(k10, qf0, s1, 0, 0, 0);                    \
        s1 = __builtin_amdgcn_mfma_f32_16x16x32_bf16(k11, qf1, s1, 0, 0, 0);                    \
        bf16x8 pf;                                                                              \
        pf[0] = (__bf16)__builtin_amdgcn_exp2f(s0[0]);                                          \
        pf[1] = (__bf16)__builtin_amdgcn_exp2f(s0[1]);                                          \
        pf[2] = (__bf16)__builtin_amdgcn_exp2f(s0[2]);                                          \
        pf[3] = (__bf16)__builtin_amdgcn_exp2f(s0[3]);                                          \
        pf[4] = (__bf16)__builtin_amdgcn_exp2f(s1[0]);                                          \
        pf[5] = (__bf16)__builtin_amdgcn_exp2f(s1[1]);                                          \
        pf[6] = (__bf16)__builtin_amdgcn_exp2f(s1[2]);                                          \
        pf[7] = (__bf16)__builtin_amdgcn_exp2f(s1[3]);                                          \
        ors = __builtin_amdgcn_mfma_f32_16x16x32_bf16(pf, onesf, ors, 0, 0, 0);                 \
        o0 = __builtin_amdgcn_mfma_f32_16x16x32_bf16(pf, v0, o0, 0, 0, 0);                      \
        o1 = __builtin_amdgcn_mfma_f32_16x16x32_bf16(pf, v1, o1, 0, 0, 0);                      \
        o2 = __builtin_amdgcn_mfma_f32_16x16x32_bf16(pf, v2, o2, 0, 0, 0);                      \
        o3 = __builtin_amdgcn_mfma_f32_16x16x32_bf16(pf, v3, o3, 0, 0, 0);                      \
    }

    STAGE(0, 0)
    __syncthreads();

    for (int t = 0; t < 32; t += 2) {
        if (t + 1 < 32) { STAGE(1, (t + 1) * 64) }
        COMPUTE(Klds[0], Vlds[0], 0,    av0)
        COMPUTE(Klds[0], Vlds[0], 2048, av1)
        __syncthreads();
        if (t + 2 < 32) { STAGE(0, (t + 2) * 64) }
        COMPUTE(Klds[1], Vlds[1], 0,    av0)
        COMPUTE(Klds[1], Vlds[1], 2048, av1)
        __syncthreads();
    }
#undef STAGE
#undef COMPUTE

#pragma unroll
    for (int r = 0; r < 4; ++r) {
        float inv = 1.0f / ors[r];
        size_t row = ((size_t)b * N_ + qbase + lg * 4 + r) * QD_ + h * D_ + l15;
        AO[row +  0] = (__bf16)(o0[r] * inv);
        AO[row + 16] = (__bf16)(o1[r] * inv);
        AO[row + 32] = (__bf16)(o2[r] * inv);
        AO[row + 48] = (__bf16)(o3[r] * inv);
    }
}

// ---------------------------------------------------------------------------
extern "C" void kernel_launch(void* const* d_in, const int* in_sizes, int n_in,
                              void* d_out, int out_size, void* d_ws, size_t ws_size,
                              hipStream_t stream) {
    const float* x   = (const float*)d_in[0];
    const float* ctx = (const float*)d_in[1];
    const float* Wq  = (const float*)d_in[2];
    const float* Wk  = (const float*)d_in[3];
    const float* Wv  = (const float*)d_in[4];
    const float* Wo  = (const float*)d_in[5];

    char* ws = (char*)d_ws;
    __bf16* xb  = (__bf16*)(ws);                      // 0-8 MB
    __bf16* cb  = (__bf16*)(ws + (8u  << 20));        // 8-16 MB
    __bf16* Wtq = (__bf16*)(ws + (16u << 20));        // 16-18 MB
    __bf16* Wtk = (__bf16*)(ws + (18u << 20));        // 18-20
    __bf16* Wtv = (__bf16*)(ws + (20u << 20));        // 20-22
    __bf16* Wto = (__bf16*)(ws + (22u << 20));        // 22-24
    __bf16* Qb  = (__bf16*)(ws + (24u << 20));        // 24-32  [bh][2048][64], pre-scaled
    __bf16* Kb  = (__bf16*)(ws + (32u << 20));        // 32-40  [bh][2048][64]
    __bf16* Vt  = (__bf16*)(ws + (40u << 20));        // 40-48  [bh][64][2048]
    __bf16* AO  = (__bf16*)(ws + (48u << 20));        // 48-56  [4096][1024]

    cvt2_f32_bf16<<<dim3(4096, 2), 256, 0, stream>>>(x, ctx, xb, cb);
    transpose4_cvt<<<dim3(16, 16, 4), 256, 0, stream>>>(Wq, Wk, Wv, Wo, Wtq, Wtk, Wtv, Wto);
    gemm_qkv<<<dim3(32, 8, 3), 256, 0, stream>>>(xb, cb, Wtq, Wtk, Wtv, Qb, Kb, Vt);
    attn_kernel<<<512, 512, 0, stream>>>(Qb, Kb, Vt, AO);
    gemm_out<<<dim3(32, 8), 256, 0, stream>>>(AO, Wto, (float*)d_out);
}